// Round 3
// baseline (383.026 us; speedup 1.0000x reference)
//
#include <hip/hip_runtime.h>
#include <stdint.h>

#define DEVI __device__ __forceinline__

typedef short bf16x8 __attribute__((ext_vector_type(8)));
typedef float f32x4 __attribute__((ext_vector_type(4)));

// analytically-derived max of the gamma positional basis (i=0, ap=36):
// exp(3*ln36 - 3 - ln6 - 4*ln12) = 0.01867013 (input-independent constant)
#define PMAX 0.01867013f

DEVI float b2f(unsigned short u) {
  union { unsigned u32; float f; } x;
  x.u32 = ((unsigned)u) << 16;
  return x.f;
}
DEVI unsigned short f2b(float f) {
  union { float f32; unsigned u32; } x;
  x.f32 = f;
  unsigned u = x.u32;
  return (unsigned short)((u + 0x7FFFu + ((u >> 16) & 1u)) >> 16);
}

// async global->LDS, 16B per lane. LDS dest must be wave-uniform base + lane*16.
DEVI void gload16(const unsigned short* g, unsigned short* l) {
  __builtin_amdgcn_global_load_lds(
      (const __attribute__((address_space(1))) void*)g,
      (__attribute__((address_space(3))) void*)l, 16, 0, 0);
}

DEVI float gamma_prob(float ap, int i) {
  float mean = 48.f * (float)(i + 1);
  float conc = (mean / 24.f) * (mean / 24.f);
  float rate = mean / 576.f;
  if (ap == 0.f) return 1e-8f;
  float logp = (conc - 1.f) * logf(ap) - rate * ap - (lgammaf(conc) - conc * logf(rate));
  return expf(logp) + 1e-8f;
}

// ---------------------------------------------------- device transpose (32x32)
DEVI void dev_transpose(const float* srcf, const unsigned short* srcb, int src_ld,
                        unsigned short* dst, int dst_ld, int rows, int cols,
                        int bx, int by, unsigned short (*t)[33]) {
  int tx = threadIdx.x & 31, ty = threadIdx.x >> 5;
  int r0 = by * 32, c0 = bx * 32;
#pragma unroll
  for (int i = 0; i < 4; i++) {
    int r = r0 + ty + i * 8, cc = c0 + tx;
    if (r < rows && cc < cols)
      t[ty + i * 8][tx] = srcf ? f2b(srcf[(size_t)r * src_ld + cc])
                               : srcb[(size_t)r * src_ld + cc];
  }
  __syncthreads();
#pragma unroll
  for (int i = 0; i < 4; i++) {
    int dr = c0 + ty + i * 8, dc = r0 + tx;
    if (dr < cols && dc < rows) dst[(size_t)dr * dst_ld + dc] = t[tx][ty + i * 8];
  }
}

// ------------------------------------------------------------------ k_prep
// segments: [0,4608) x->bf16 (x4); [4608,5376) Wq^T; [5376,6144) Wk^T;
// [6144,8448) Wv^T; [8448,10752) Wemb^T; [10752,10848) Wrk^T; [10848,12000) emb
__global__ __launch_bounds__(256) void k_prep(
    const float* __restrict__ x, const float* __restrict__ Wq,
    const float* __restrict__ Wk, const float* __restrict__ Wv,
    const float* __restrict__ Wemb, const float* __restrict__ Wrk,
    unsigned short* __restrict__ xb, unsigned short* __restrict__ WqkvT,
    unsigned short* __restrict__ WembT, unsigned short* __restrict__ WrkT,
    unsigned short* __restrict__ emb) {
  __shared__ unsigned short t[32][33];
  int bid = blockIdx.x;
  if (bid < 4608) {
    int i = (bid * 256 + threadIdx.x) * 4;
    float4 v = *(const float4*)(x + i);
    ushort4 o;
    o.x = f2b(v.x); o.y = f2b(v.y); o.z = f2b(v.z); o.w = f2b(v.w);
    *(ushort4*)(xb + i) = o;
  } else if (bid < 5376) {
    int s = bid - 4608;
    dev_transpose(Wq, nullptr, 512, WqkvT, 1536, 1536, 512, s % 16, s / 16, t);
  } else if (bid < 6144) {
    int s = bid - 5376;
    dev_transpose(Wk, nullptr, 512, WqkvT + (size_t)512 * 1536, 1536, 1536, 512, s % 16, s / 16, t);
  } else if (bid < 8448) {
    int s = bid - 6144;
    dev_transpose(Wv, nullptr, 1536, WqkvT + (size_t)1024 * 1536, 1536, 1536, 1536, s % 48, s / 48, t);
  } else if (bid < 10752) {
    int s = bid - 8448;
    dev_transpose(Wemb, nullptr, 1536, WembT, 1536, 1536, 1536, s % 48, s / 48, t);
  } else if (bid < 10848) {
    int s = bid - 10752;
    dev_transpose(Wrk, nullptr, 512, WrkT, 192, 192, 512, s % 16, s / 16, t);
  } else {
    int idx = (bid - 10848) * 256 + threadIdx.x;
    if (idx < 3071 * 96) {
      int m = idx / 96, cc = idx % 96;
      float ap = fabsf((float)(m - 1535));
      float val;
      if (cc < 32) {
        float max_range = logf(1536.f) * 1.4426950408889634f;
        float l = 3.f + (float)cc * (max_range - 3.f) / 31.f;
        val = exp2f(-ap * exp2f(-l));
      } else if (cc < 64) {
        float width = exp2f((float)(cc - 31)) - 1.f;
        val = (width > ap) ? 1.f : 0.f;
      } else {
        val = gamma_prob(ap, cc - 64) / PMAX;
      }
      float sgn = (m > 1535) ? 1.f : ((m < 1535) ? -1.f : 0.f);
      emb[(size_t)m * 192 + cc] = f2b(val);
      emb[(size_t)m * 192 + 96 + cc] = f2b(sgn * val);
    }
  }
}

// ---------------------------------------------------------------- MFMA GEMM
DEVI void dev_gemm(const unsigned short* __restrict__ A, const unsigned short* __restrict__ Bt,
                   unsigned short* Cb, float* Cf, int M, int N, int K,
                   int bx, int by, unsigned short* As, unsigned short* Bs) {
  int tid = threadIdx.x;
  int w = tid >> 6, L = tid & 63, g = L >> 4, c = L & 15;
  int m0 = by << 7, n0 = bx << 7;
  int wm = (w >> 1) << 6, wn = (w & 1) << 6;
  f32x4 acc[4][4];
#pragma unroll
  for (int i = 0; i < 4; i++)
#pragma unroll
    for (int j = 0; j < 4; j++) acc[i][j] = (f32x4){0.f, 0.f, 0.f, 0.f};
  int nkt = K >> 5;
  for (int kt = 0; kt < nkt; kt++) {
    int k0 = kt << 5;
#pragma unroll
    for (int i2 = 0; i2 < 2; i2++) {
      int cidx = tid + (i2 << 8);
      int row = cidx >> 2, kc = (cidx & 3) << 3;
      int ra = m0 + row;
      if (ra >= M) ra = M - 1;
      gload16(A + (size_t)ra * K + k0 + kc, As + cidx * 8);
      gload16(Bt + (size_t)(n0 + row) * K + k0 + kc, Bs + cidx * 8);
    }
    __syncthreads();
    bf16x8 af[4], bfr[4];
#pragma unroll
    for (int t = 0; t < 4; t++) af[t] = *(const bf16x8*)(As + (wm + t * 16 + c) * 32 + g * 8);
#pragma unroll
    for (int t = 0; t < 4; t++) bfr[t] = *(const bf16x8*)(Bs + (wn + t * 16 + c) * 32 + g * 8);
#pragma unroll
    for (int mt = 0; mt < 4; mt++)
#pragma unroll
      for (int nt = 0; nt < 4; nt++)
        acc[mt][nt] = __builtin_amdgcn_mfma_f32_16x16x32_bf16(af[mt], bfr[nt], acc[mt][nt], 0, 0, 0);
    __syncthreads();
  }
#pragma unroll
  for (int mt = 0; mt < 4; mt++)
#pragma unroll
    for (int nt = 0; nt < 4; nt++)
#pragma unroll
      for (int r = 0; r < 4; r++) {
        int rr = m0 + wm + mt * 16 + g * 4 + r;
        if (rr < M) {
          size_t o = (size_t)rr * N + n0 + wn + nt * 16 + c;
          if (Cf) Cf[o] = acc[mt][nt][r];
          else Cb[o] = f2b(acc[mt][nt][r]);
        }
      }
}

__global__ __launch_bounds__(256) void k_gemm(
    const unsigned short* __restrict__ A, const unsigned short* __restrict__ Bt,
    unsigned short* Cb, float* Cf, int M, int N, int K) {
  __shared__ unsigned short sm[8192];
  dev_gemm(A, Bt, Cb, Cf, M, N, K, blockIdx.x, blockIdx.y, sm, sm + 4096);
}

// ------------------------------------------------------------------ k_mid
// [0,96): rel-key GEMM emb[3071,192] x WrkT[512,192]^T -> rkb
// [96,4704): Vt transposes for both batches
__global__ __launch_bounds__(256) void k_mid(
    const unsigned short* __restrict__ emb, const unsigned short* __restrict__ WrkT,
    unsigned short* __restrict__ rkb, const unsigned short* __restrict__ QKV,
    unsigned short* __restrict__ Vt) {
  __shared__ unsigned short sm[8192];
  int bid = blockIdx.x;
  if (bid < 96) {
    dev_gemm(emb, WrkT, rkb, nullptr, 3071, 512, 192, bid & 3, bid >> 2, sm, sm + 4096);
  } else {
    int tt = bid - 96;
    int which = tt / 2304;
    tt %= 2304;
    dev_transpose(nullptr, QKV + 1024 + (size_t)which * 1536 * 2560, 2560,
                  Vt + (size_t)which * 1536 * 1536, 1536, 1536, 1536,
                  tt % 48, tt / 48, (unsigned short (*)[33])sm);
  }
}

// ------------------------------------------------------------ flash attention
// QBLK=32 RESTRUCTURE (r3): r0/r2 post-mortem showed k_attn is bound by L2
// traffic (~1.5 GB total at ~8.4 TB/s achieved), not wave slots (r1) nor
// load-latency exposure (r2 null). Each block re-reads full K/V/rk (~1MB)
// but amortized over only 16 q-rows. Fix: 512-thread blocks, 8 waves =
// 2 q-subtiles x 4 key-quarters. Per-wave inner loop IDENTICAL to the proven
// r0 loop (no main-loop barriers, deep V prefetch, per-wave P slabs); the two
// waves sharing a key-quarter read identical K/V lines (L1-served dup) and
// 80%-overlapping rk bands -> per-block L2 traffic stays ~1MB while serving
// 32 q-rows => total L2 traffic halves to ~0.77 GB. Grid 768, bid&7=h keeps
// the XCD swizzle. VGPR ~108 -> 2 blocks/CU = 16 waves/CU (2x r0's TLP).
// NO online-softmax: logits provably |.| <~ 5, p = exp(lg) directly.
__global__ __launch_bounds__(512, 2) void k_attn(
    const unsigned short* __restrict__ QKV, const unsigned short* __restrict__ rk,
    const unsigned short* __restrict__ Vt, const float* __restrict__ rwb,
    const float* __restrict__ rrb, unsigned short* __restrict__ O) {
  // floats: P bufs u16[0,18432) = [0,9216); mll floats [9216,9344)
  __shared__ float smem[9344];
  const int tid = threadIdx.x;
  const int w = tid >> 6, L = tid & 63, g = L >> 4, c = L & 15;
  const int qs = w >> 2, kq = w & 3;
  unsigned short* pw0 = (unsigned short*)smem + w * 1152;         // 16x72 u16
  unsigned short* pw1 = (unsigned short*)smem + 9216 + w * 1152;  // parity buddy
  const int bid = blockIdx.x;
  const int h = bid & 7, b = (bid >> 3) & 1;
  const int i0 = ((bid >> 4) << 5) + (qs << 4);  // this wave's 16-row q-tile
  const int bh = b * 8 + h;

  // two Q fragments (A-operand): content uses rwb, rel uses rrb
  bf16x8 aqw[2], aqr[2];
  {
    const unsigned short* qrow = QKV + (size_t)(b * 1536 + i0 + c) * 2560 + h * 64;
#pragma unroll
    for (int ks = 0; ks < 2; ks++) {
      union { bf16x8 v; unsigned short s[8]; } uw, ur;
#pragma unroll
      for (int j = 0; j < 8; j++) {
        int d = ks * 32 + g * 8 + j;
        float qv = b2f(qrow[d]) * 0.125f;
        uw.s[j] = f2b(qv + rwb[h * 64 + d]);
        ur.s[j] = f2b(qv + rrb[h * 64 + d]);
      }
      aqw[ks] = uw.v;
      aqr[ks] = ur.v;
    }
  }

  // bpermute addresses / selects for the folded relative shift
  int baddr[4], bsel[4];
#pragma unroll
  for (int r = 0; r < 4; r++) {
    int u = c - (g * 4 + r) + 15;  // in [0,30]
    baddr[r] = (((g << 4) | (u & 15)) << 2);
    bsel[r] = (u >> 4) & 1;
  }

  f32x4 Ofr[12];
#pragma unroll
  for (int t = 0; t < 12; t++) Ofr[t] = (f32x4){0.f, 0.f, 0.f, 0.f};
  float lrow[4] = {0.f, 0.f, 0.f, 0.f};  // per-lane partial sum (no max tracking)

  const size_t kbase = (size_t)(b * 1536) * 2560 + 512 + h * 64;
  const unsigned short* vtb = Vt + (size_t)(bh * 192) * 1536;

  for (int jt = 0; jt < 6; jt++) {
    const int j0 = kq * 384 + jt * 64;
    const int moff = j0 - i0 + 1520;
    unsigned short* pwb = (jt & 1) ? pw1 : pw0;
    // ---- prefetch V first halves (latency hides under content+rel+exp)
    bf16x8 vfA[12];
#pragma unroll
    for (int nt3 = 0; nt3 < 12; nt3++)
      vfA[nt3] = *(const bf16x8*)(vtb + (size_t)(nt3 * 16 + c) * 1536 + j0 + g * 8);
    // ---- content scores
    f32x4 Sc[4];
#pragma unroll
    for (int nt = 0; nt < 4; nt++) {
      const unsigned short* krow = QKV + kbase + (size_t)(j0 + nt * 16 + c) * 2560;
      f32x4 z = (f32x4){0.f, 0.f, 0.f, 0.f};
      z = __builtin_amdgcn_mfma_f32_16x16x32_bf16(aqw[0], *(const bf16x8*)(krow + g * 8), z, 0, 0, 0);
      z = __builtin_amdgcn_mfma_f32_16x16x32_bf16(aqw[1], *(const bf16x8*)(krow + 32 + g * 8), z, 0, 0, 0);
      Sc[nt] = z;
    }
    // ---- rel band, rolling 2-tile window
    float lg[4][4], bandp[4];
    {
      int mg = moff + c;
      const unsigned short* rrow = rk + (size_t)mg * 512 + h * 64;
      f32x4 z = (f32x4){0.f, 0.f, 0.f, 0.f};
      z = __builtin_amdgcn_mfma_f32_16x16x32_bf16(aqr[0], *(const bf16x8*)(rrow + g * 8), z, 0, 0, 0);
      z = __builtin_amdgcn_mfma_f32_16x16x32_bf16(aqr[1], *(const bf16x8*)(rrow + 32 + g * 8), z, 0, 0, 0);
#pragma unroll
      for (int r = 0; r < 4; r++)
        bandp[r] = __int_as_float(__builtin_amdgcn_ds_bpermute(baddr[r], __float_as_int(z[r])));
    }
#pragma unroll
    for (int nt = 0; nt < 4; nt++) {
      int mg = moff + (nt + 1) * 16 + c;
      if (mg > 3070) mg = 3070;  // clamped lane (t'=79) is never consumed
      const unsigned short* rrow = rk + (size_t)mg * 512 + h * 64;
      f32x4 z = (f32x4){0.f, 0.f, 0.f, 0.f};
      z = __builtin_amdgcn_mfma_f32_16x16x32_bf16(aqr[0], *(const bf16x8*)(rrow + g * 8), z, 0, 0, 0);
      z = __builtin_amdgcn_mfma_f32_16x16x32_bf16(aqr[1], *(const bf16x8*)(rrow + 32 + g * 8), z, 0, 0, 0);
#pragma unroll
      for (int r = 0; r < 4; r++) {
        float bandc = __int_as_float(__builtin_amdgcn_ds_bpermute(baddr[r], __float_as_int(z[r])));
        lg[nt][r] = Sc[nt][r] + (bsel[r] ? bandc : bandp[r]);
        bandp[r] = bandc;
      }
    }
    // ---- p = exp(logit), accumulate per-lane partial sums (no shuffles here)
#pragma unroll
    for (int nt = 0; nt < 4; nt++)
#pragma unroll
      for (int r = 0; r < 4; r++) {
        float p = __expf(lg[nt][r]);
        lg[nt][r] = p;
        lrow[r] += p;
      }
    // ---- P -> per-wave LDS (parity-buffered), PV MFMA (no rescale)
#pragma unroll
    for (int nt = 0; nt < 4; nt++)
#pragma unroll
      for (int r = 0; r < 4; r++) pwb[(g * 4 + r) * 72 + nt * 16 + c] = f2b(lg[nt][r]);
    // order P-write before P-read at the scheduler level while still letting
    // global loads / MFMA / VALU migrate across (0x7F = everything except DS)
    __builtin_amdgcn_sched_barrier(0x7F);
    bf16x8 ap0 = *(const bf16x8*)(pwb + c * 72 + g * 8);
    bf16x8 ap1 = *(const bf16x8*)(pwb + c * 72 + 32 + g * 8);
    __builtin_amdgcn_sched_barrier(0x7F);
    __builtin_amdgcn_s_setprio(1);
#pragma unroll
    for (int nt3 = 0; nt3 < 12; nt3++) {
      bf16x8 vb2 = *(const bf16x8*)(vtb + (size_t)(nt3 * 16 + c) * 1536 + j0 + 32 + g * 8);
      Ofr[nt3] = __builtin_amdgcn_mfma_f32_16x16x32_bf16(ap0, vfA[nt3], Ofr[nt3], 0, 0, 0);
      Ofr[nt3] = __builtin_amdgcn_mfma_f32_16x16x32_bf16(ap1, vb2, Ofr[nt3], 0, 0, 0);
    }
    __builtin_amdgcn_s_setprio(0);
  }

  // ---- one-time reduction of lrow over the 16 c-lanes of each row
#pragma unroll
  for (int r = 0; r < 4; r++) {
    float s = lrow[r];
    s += __shfl_xor(s, 1, 64);
    s += __shfl_xor(s, 2, 64);
    s += __shfl_xor(s, 4, 64);
    s += __shfl_xor(s, 8, 64);
    lrow[r] = s;
  }
  // ---- per-q-subtile merge: scale = 1 / sum of the 4 key-quarter wave-sums
  float* mll = smem + 9216;  // [qs*64 + kq*16 + q], 128 floats
  if (c == 0)
#pragma unroll
    for (int r = 0; r < 4; r++) mll[qs * 64 + kq * 16 + g * 4 + r] = lrow[r];
  __syncthreads();
  float scale[4];
#pragma unroll
  for (int r = 0; r < 4; r++) {
    int q = qs * 64 + g * 4 + r;
    scale[r] = 1.f / (mll[q] + mll[16 + q] + mll[32 + q] + mll[48 + q]);
  }
#pragma unroll
  for (int t = 0; t < 12; t++)
#pragma unroll
    for (int r = 0; r < 4; r++) Ofr[t][r] *= scale[r];
  // chunked publish-sum per q-subtile: 4 chunks of 3 v-tiles (48 cols);
  // qs=0 uses float region [0,3072), qs=1 [3072,6144) -- alias P bufs (done).
  const int t2 = tid & 255;
  const int qo = t2 >> 4, v3 = (t2 & 15) * 3;
  float* base = smem + qs * 3072;
  unsigned short* orow = O + (size_t)(b * 1536 + i0 + qo - (qs << 4)) * 1536 + h * 192;
  // note: i0 already includes qs*16; row index for the read-back phase is
  // i0 - qs*16 + qs*16 + qo = block base + qs*16 + qo. The (qs<<4) terms cancel:
  orow = O + (size_t)(b * 1536 + ((bid >> 4) << 5) + (qs << 4) + qo) * 1536 + h * 192;
  for (int c4 = 0; c4 < 4; c4++) {
    __syncthreads();
    float* slot = base + kq * 768;
#pragma unroll
    for (int tl = 0; tl < 3; tl++)
#pragma unroll
      for (int r = 0; r < 4; r++)
        slot[(g * 4 + r) * 48 + tl * 16 + c] = Ofr[c4 * 3 + tl][r];
    __syncthreads();
#pragma unroll
    for (int k = 0; k < 3; k++) {
      int v = v3 + k;
      float s = base[qo * 48 + v] + base[768 + qo * 48 + v] +
                base[1536 + qo * 48 + v] + base[2304 + qo * 48 + v];
      orow[c4 * 48 + v] = f2b(s);
    }
  }
}

// ------------------------------------------------------------------ launcher
extern "C" void kernel_launch(void* const* d_in, const int* in_sizes, int n_in,
                              void* d_out, int out_size, void* d_ws, size_t ws_size,
                              hipStream_t stream) {
  const float* x    = (const float*)d_in[0];
  const float* Wq   = (const float*)d_in[1];
  const float* Wk   = (const float*)d_in[2];
  const float* Wv   = (const float*)d_in[3];
  const float* Wrk  = (const float*)d_in[4];
  const float* Wemb = (const float*)d_in[5];
  const float* rwb  = (const float*)d_in[6];
  const float* rrb  = (const float*)d_in[7];

  char* ws = (char*)d_ws;
  size_t off = 0;
  auto alloc = [&](size_t bytes) -> void* {
    void* p = ws + off;
    off += (bytes + 255) & ~(size_t)255;
    return p;
  };
  unsigned short* xb    = (unsigned short*)alloc((size_t)3072 * 1536 * 2);
  unsigned short* WqkvT = (unsigned short*)alloc((size_t)2560 * 1536 * 2);
  unsigned short* WembT = (unsigned short*)alloc((size_t)1536 * 1536 * 2);
  unsigned short* WrkT  = (unsigned short*)alloc((size_t)512 * 192 * 2);
  unsigned short* QKV   = (unsigned short*)alloc((size_t)3072 * 2560 * 2);
  unsigned short* Vt    = (unsigned short*)alloc((size_t)2 * 1536 * 1536 * 2);
  unsigned short* emb   = (unsigned short*)alloc((size_t)3072 * 192 * 2);
  unsigned short* rkb   = (unsigned short*)alloc((size_t)3072 * 512 * 2);
  unsigned short* Obuf  = (unsigned short*)alloc((size_t)3072 * 1536 * 2);

  // 1) fused prep: x->bf16, 5 weight transposes, positional emb (pmax const)
  k_prep<<<12000, 256, 0, stream>>>(x, Wq, Wk, Wv, Wemb, Wrk, xb, WqkvT, WembT, WrkT, emb);
  // 2) fused QKV projection
  k_gemm<<<dim3(20, 24), 256, 0, stream>>>(xb, WqkvT, QKV, nullptr, 3072, 2560, 1536);
  // 3) rel-key GEMM + V transposes
  k_mid<<<4704, 256, 0, stream>>>(emb, WrkT, rkb, QKV, Vt);
  // 4) flash attention (QBLK=32, 8 waves: 2 q-subtiles x 4 key-quarters)
  k_attn<<<768, 512, 0, stream>>>(QKV, rkb, Vt, rwb, rrb, Obuf);
  // 5) output projection -> f32 d_out
  k_gemm<<<dim3(12, 24), 256, 0, stream>>>(Obuf, WembT, nullptr, (float*)d_out, 3072, 1536, 1536);
}

// Round 4
// 313.863 us; speedup vs baseline: 1.2204x; 1.2204x over previous
//
#include <hip/hip_runtime.h>
#include <stdint.h>

#define DEVI __device__ __forceinline__

typedef short bf16x8 __attribute__((ext_vector_type(8)));
typedef float f32x4 __attribute__((ext_vector_type(4)));

// analytically-derived max of the gamma positional basis (i=0, ap=36):
// exp(3*ln36 - 3 - ln6 - 4*ln12) = 0.01867013 (input-independent constant)
#define PMAX 0.01867013f

DEVI float b2f(unsigned short u) {
  union { unsigned u32; float f; } x;
  x.u32 = ((unsigned)u) << 16;
  return x.f;
}
DEVI unsigned short f2b(float f) {
  union { float f32; unsigned u32; } x;
  x.f32 = f;
  unsigned u = x.u32;
  return (unsigned short)((u + 0x7FFFu + ((u >> 16) & 1u)) >> 16);
}

// async global->LDS, 16B per lane. LDS dest must be wave-uniform base + lane*16.
DEVI void gload16(const unsigned short* g, unsigned short* l) {
  __builtin_amdgcn_global_load_lds(
      (const __attribute__((address_space(1))) void*)g,
      (__attribute__((address_space(3))) void*)l, 16, 0, 0);
}

DEVI float gamma_prob(float ap, int i) {
  float mean = 48.f * (float)(i + 1);
  float conc = (mean / 24.f) * (mean / 24.f);
  float rate = mean / 576.f;
  if (ap == 0.f) return 1e-8f;
  float logp = (conc - 1.f) * logf(ap) - rate * ap - (lgammaf(conc) - conc * logf(rate));
  return expf(logp) + 1e-8f;
}

// ---------------------------------------------------- device transpose (32x32)
DEVI void dev_transpose(const float* srcf, const unsigned short* srcb, int src_ld,
                        unsigned short* dst, int dst_ld, int rows, int cols,
                        int bx, int by, unsigned short (*t)[33]) {
  int tx = threadIdx.x & 31, ty = threadIdx.x >> 5;
  int r0 = by * 32, c0 = bx * 32;
#pragma unroll
  for (int i = 0; i < 4; i++) {
    int r = r0 + ty + i * 8, cc = c0 + tx;
    if (r < rows && cc < cols)
      t[ty + i * 8][tx] = srcf ? f2b(srcf[(size_t)r * src_ld + cc])
                               : srcb[(size_t)r * src_ld + cc];
  }
  __syncthreads();
#pragma unroll
  for (int i = 0; i < 4; i++) {
    int dr = c0 + ty + i * 8, dc = r0 + tx;
    if (dr < cols && dc < rows) dst[(size_t)dr * dst_ld + dc] = t[tx][ty + i * 8];
  }
}

// ------------------------------------------------------------------ k_prep
// segments: [0,4608) x->bf16 (x4); [4608,5376) Wq^T; [5376,6144) Wk^T;
// [6144,8448) Wv^T; [8448,10752) Wemb^T; [10752,10848) Wrk^T; [10848,12000) emb
__global__ __launch_bounds__(256) void k_prep(
    const float* __restrict__ x, const float* __restrict__ Wq,
    const float* __restrict__ Wk, const float* __restrict__ Wv,
    const float* __restrict__ Wemb, const float* __restrict__ Wrk,
    unsigned short* __restrict__ xb, unsigned short* __restrict__ WqkvT,
    unsigned short* __restrict__ WembT, unsigned short* __restrict__ WrkT,
    unsigned short* __restrict__ emb) {
  __shared__ unsigned short t[32][33];
  int bid = blockIdx.x;
  if (bid < 4608) {
    int i = (bid * 256 + threadIdx.x) * 4;
    float4 v = *(const float4*)(x + i);
    ushort4 o;
    o.x = f2b(v.x); o.y = f2b(v.y); o.z = f2b(v.z); o.w = f2b(v.w);
    *(ushort4*)(xb + i) = o;
  } else if (bid < 5376) {
    int s = bid - 4608;
    dev_transpose(Wq, nullptr, 512, WqkvT, 1536, 1536, 512, s % 16, s / 16, t);
  } else if (bid < 6144) {
    int s = bid - 5376;
    dev_transpose(Wk, nullptr, 512, WqkvT + (size_t)512 * 1536, 1536, 1536, 512, s % 16, s / 16, t);
  } else if (bid < 8448) {
    int s = bid - 6144;
    dev_transpose(Wv, nullptr, 1536, WqkvT + (size_t)1024 * 1536, 1536, 1536, 1536, s % 48, s / 48, t);
  } else if (bid < 10752) {
    int s = bid - 8448;
    dev_transpose(Wemb, nullptr, 1536, WembT, 1536, 1536, 1536, s % 48, s / 48, t);
  } else if (bid < 10848) {
    int s = bid - 10752;
    dev_transpose(Wrk, nullptr, 512, WrkT, 192, 192, 512, s % 16, s / 16, t);
  } else {
    int idx = (bid - 10848) * 256 + threadIdx.x;
    if (idx < 3071 * 96) {
      int m = idx / 96, cc = idx % 96;
      float ap = fabsf((float)(m - 1535));
      float val;
      if (cc < 32) {
        float max_range = logf(1536.f) * 1.4426950408889634f;
        float l = 3.f + (float)cc * (max_range - 3.f) / 31.f;
        val = exp2f(-ap * exp2f(-l));
      } else if (cc < 64) {
        float width = exp2f((float)(cc - 31)) - 1.f;
        val = (width > ap) ? 1.f : 0.f;
      } else {
        val = gamma_prob(ap, cc - 64) / PMAX;
      }
      float sgn = (m > 1535) ? 1.f : ((m < 1535) ? -1.f : 0.f);
      emb[(size_t)m * 192 + cc] = f2b(val);
      emb[(size_t)m * 192 + 96 + cc] = f2b(sgn * val);
    }
  }
}

// ---------------------------------------------------------------- MFMA GEMM
DEVI void dev_gemm(const unsigned short* __restrict__ A, const unsigned short* __restrict__ Bt,
                   unsigned short* Cb, float* Cf, int M, int N, int K,
                   int bx, int by, unsigned short* As, unsigned short* Bs) {
  int tid = threadIdx.x;
  int w = tid >> 6, L = tid & 63, g = L >> 4, c = L & 15;
  int m0 = by << 7, n0 = bx << 7;
  int wm = (w >> 1) << 6, wn = (w & 1) << 6;
  f32x4 acc[4][4];
#pragma unroll
  for (int i = 0; i < 4; i++)
#pragma unroll
    for (int j = 0; j < 4; j++) acc[i][j] = (f32x4){0.f, 0.f, 0.f, 0.f};
  int nkt = K >> 5;
  for (int kt = 0; kt < nkt; kt++) {
    int k0 = kt << 5;
#pragma unroll
    for (int i2 = 0; i2 < 2; i2++) {
      int cidx = tid + (i2 << 8);
      int row = cidx >> 2, kc = (cidx & 3) << 3;
      int ra = m0 + row;
      if (ra >= M) ra = M - 1;
      gload16(A + (size_t)ra * K + k0 + kc, As + cidx * 8);
      gload16(Bt + (size_t)(n0 + row) * K + k0 + kc, Bs + cidx * 8);
    }
    __syncthreads();
    bf16x8 af[4], bfr[4];
#pragma unroll
    for (int t = 0; t < 4; t++) af[t] = *(const bf16x8*)(As + (wm + t * 16 + c) * 32 + g * 8);
#pragma unroll
    for (int t = 0; t < 4; t++) bfr[t] = *(const bf16x8*)(Bs + (wn + t * 16 + c) * 32 + g * 8);
#pragma unroll
    for (int mt = 0; mt < 4; mt++)
#pragma unroll
      for (int nt = 0; nt < 4; nt++)
        acc[mt][nt] = __builtin_amdgcn_mfma_f32_16x16x32_bf16(af[mt], bfr[nt], acc[mt][nt], 0, 0, 0);
    __syncthreads();
  }
#pragma unroll
  for (int mt = 0; mt < 4; mt++)
#pragma unroll
    for (int nt = 0; nt < 4; nt++)
#pragma unroll
      for (int r = 0; r < 4; r++) {
        int rr = m0 + wm + mt * 16 + g * 4 + r;
        if (rr < M) {
          size_t o = (size_t)rr * N + n0 + wn + nt * 16 + c;
          if (Cf) Cf[o] = acc[mt][nt][r];
          else Cb[o] = f2b(acc[mt][nt][r]);
        }
      }
}

__global__ __launch_bounds__(256) void k_gemm(
    const unsigned short* __restrict__ A, const unsigned short* __restrict__ Bt,
    unsigned short* Cb, float* Cf, int M, int N, int K) {
  __shared__ unsigned short sm[8192];
  dev_gemm(A, Bt, Cb, Cf, M, N, K, blockIdx.x, blockIdx.y, sm, sm + 4096);
}

// ------------------------------------------------------------------ k_mid
// [0,96): rel-key GEMM emb[3071,192] x WrkT[512,192]^T -> rkb
// [96,4704): Vt transposes for both batches
__global__ __launch_bounds__(256) void k_mid(
    const unsigned short* __restrict__ emb, const unsigned short* __restrict__ WrkT,
    unsigned short* __restrict__ rkb, const unsigned short* __restrict__ QKV,
    unsigned short* __restrict__ Vt) {
  __shared__ unsigned short sm[8192];
  int bid = blockIdx.x;
  if (bid < 96) {
    dev_gemm(emb, WrkT, rkb, nullptr, 3071, 512, 192, bid & 3, bid >> 2, sm, sm + 4096);
  } else {
    int tt = bid - 96;
    int which = tt / 2304;
    tt %= 2304;
    dev_transpose(nullptr, QKV + 1024 + (size_t)which * 1536 * 2560, 2560,
                  Vt + (size_t)which * 1536 * 1536, 1536, 1536, 1536,
                  tt % 48, tt / 48, (unsigned short (*)[33])sm);
  }
}

// ------------------------------------------------------------ flash attention
// r4: 2-Q-TILES-PER-WAVE REGISTER REUSE. r0-r3 post-mortems: duration pinned
// at ~185us across occupancy/ILP/L1-sharing restructures => the invariant is
// per-WAVE L2-fill traffic (each wave streams 42KB/jt through a 32KB L1 that
// thrashes; cross-wave cache sharing (r3) never materializes). Fix: reuse in
// REGISTERS, which can't be evicted. Each wave serves 32 q-rows (2 q-tiles):
//  - K fragments loaded once -> content MFMAs for both q-tiles
//  - rel band: the two 5-tile windows (offset 16) overlap 4/6 -> one union
//    pass over 6 rk tiles serves both (12 loads vs 20)
//  - V fragments loaded once -> PV MFMAs for both q-tiles (1 load : 2 MFMA)
// Per-q fill traffic: 0.52x (42KB/16q -> 44KB/32q); total 1.5GB -> 0.81GB.
// Main loop stays r0's: wave-decoupled, NO barriers, per-wave P slabs
// (parity double-buffered), sched_barrier(0x7F) DS fences, setprio on PV.
// Grid 768 = 2b x 8h x 48 qblocks; bid&7=h keeps the XCD swizzle.
// NO online-softmax: logits provably |.| <~ 5, p = exp(lg) directly.
__global__ __launch_bounds__(256, 2) void k_attn(
    const unsigned short* __restrict__ QKV, const unsigned short* __restrict__ rk,
    const unsigned short* __restrict__ Vt, const float* __restrict__ rwb,
    const float* __restrict__ rrb, unsigned short* __restrict__ O) {
  // floats: P bufs u16[0,18432) = floats [0,9216); mll floats [9216,9344)
  __shared__ float smem[9344];
  const int tid = threadIdx.x;
  const int w = tid >> 6, L = tid & 63, g = L >> 4, c = L & 15;
  const int bid = blockIdx.x;
  const int h = bid & 7, b = (bid >> 3) & 1;
  const int i0b = (bid >> 4) << 5;  // 32-row q-block base
  const int bh = b * 8 + h;

  // Q fragments for both q-subtiles: [qi][ks]; content uses rwb, rel uses rrb
  bf16x8 aqw[2][2], aqr[2][2];
#pragma unroll
  for (int qi = 0; qi < 2; qi++) {
    const unsigned short* qrow =
        QKV + (size_t)(b * 1536 + i0b + qi * 16 + c) * 2560 + h * 64;
#pragma unroll
    for (int ks = 0; ks < 2; ks++) {
      union { bf16x8 v; unsigned short s[8]; } uw, ur;
#pragma unroll
      for (int j = 0; j < 8; j++) {
        int d = ks * 32 + g * 8 + j;
        float qv = b2f(qrow[d]) * 0.125f;
        uw.s[j] = f2b(qv + rwb[h * 64 + d]);
        ur.s[j] = f2b(qv + rrb[h * 64 + d]);
      }
      aqw[qi][ks] = uw.v;
      aqr[qi][ks] = ur.v;
    }
  }

  // bpermute addresses / selects for the folded relative shift
  int baddr[4], bsel[4];
#pragma unroll
  for (int r = 0; r < 4; r++) {
    int u = c - (g * 4 + r) + 15;  // in [0,30]
    baddr[r] = (((g << 4) | (u & 15)) << 2);
    bsel[r] = (u >> 4) & 1;
  }

  f32x4 Ofr[2][12];
#pragma unroll
  for (int qi = 0; qi < 2; qi++)
#pragma unroll
    for (int t = 0; t < 12; t++) Ofr[qi][t] = (f32x4){0.f, 0.f, 0.f, 0.f};
  float lrow[2][4] = {{0.f, 0.f, 0.f, 0.f}, {0.f, 0.f, 0.f, 0.f}};

  const size_t kbase = (size_t)(b * 1536) * 2560 + 512 + h * 64;
  const unsigned short* vtb = Vt + (size_t)(bh * 192) * 1536;
  const unsigned short* rkh = rk + h * 64;

  for (int jt = 0; jt < 6; jt++) {
    const int j0 = w * 384 + jt * 64;
    // rel-window base for qi=1 (lower q-tile => larger m); qi=0 base is +16
    const int moff1 = j0 - (i0b + 16) + 1520;
    unsigned short* pwbA = (unsigned short*)smem + ((jt & 1) * 8 + w * 2 + 0) * 1152;
    unsigned short* pwbB = (unsigned short*)smem + ((jt & 1) * 8 + w * 2 + 1) * 1152;

    // ---- content scores: each K fragment feeds BOTH q-tiles
    f32x4 Sc[2][4];
#pragma unroll
    for (int nt = 0; nt < 4; nt++) {
      const unsigned short* krow = QKV + kbase + (size_t)(j0 + nt * 16 + c) * 2560;
      bf16x8 kf0 = *(const bf16x8*)(krow + g * 8);
      bf16x8 kf1 = *(const bf16x8*)(krow + 32 + g * 8);
      f32x4 z0 = (f32x4){0.f, 0.f, 0.f, 0.f};
      z0 = __builtin_amdgcn_mfma_f32_16x16x32_bf16(aqw[0][0], kf0, z0, 0, 0, 0);
      z0 = __builtin_amdgcn_mfma_f32_16x16x32_bf16(aqw[0][1], kf1, z0, 0, 0, 0);
      Sc[0][nt] = z0;
      f32x4 z1 = (f32x4){0.f, 0.f, 0.f, 0.f};
      z1 = __builtin_amdgcn_mfma_f32_16x16x32_bf16(aqw[1][0], kf0, z1, 0, 0, 0);
      z1 = __builtin_amdgcn_mfma_f32_16x16x32_bf16(aqw[1][1], kf1, z1, 0, 0, 0);
      Sc[1][nt] = z1;
    }

    // ---- rel band: single union pass over 6 rk tiles serves both windows.
    // qi=1 window = tiles j=0..4 (j=0 initial); qi=0 window = tiles j=1..5.
    float bandp0[4], bandp1[4];
    {  // j = 0: qi=1 initial only
      int mg = moff1 + c;
      const unsigned short* rrow = rkh + (size_t)mg * 512;
      bf16x8 rf0 = *(const bf16x8*)(rrow + g * 8);
      bf16x8 rf1 = *(const bf16x8*)(rrow + 32 + g * 8);
      f32x4 z = (f32x4){0.f, 0.f, 0.f, 0.f};
      z = __builtin_amdgcn_mfma_f32_16x16x32_bf16(aqr[1][0], rf0, z, 0, 0, 0);
      z = __builtin_amdgcn_mfma_f32_16x16x32_bf16(aqr[1][1], rf1, z, 0, 0, 0);
#pragma unroll
      for (int r = 0; r < 4; r++)
        bandp1[r] = __int_as_float(__builtin_amdgcn_ds_bpermute(baddr[r], __float_as_int(z[r])));
    }
#pragma unroll
    for (int j = 1; j <= 5; j++) {
      int mg = moff1 + 16 * j + c;
      if (mg > 3070) mg = 3070;  // clamped lane (band pos 79) is never consumed
      const unsigned short* rrow = rkh + (size_t)mg * 512;
      bf16x8 rf0 = *(const bf16x8*)(rrow + g * 8);
      bf16x8 rf1 = *(const bf16x8*)(rrow + 32 + g * 8);
      // qi=0 uses this tile as window index j-1
      {
        f32x4 z = (f32x4){0.f, 0.f, 0.f, 0.f};
        z = __builtin_amdgcn_mfma_f32_16x16x32_bf16(aqr[0][0], rf0, z, 0, 0, 0);
        z = __builtin_amdgcn_mfma_f32_16x16x32_bf16(aqr[0][1], rf1, z, 0, 0, 0);
        if (j == 1) {
#pragma unroll
          for (int r = 0; r < 4; r++)
            bandp0[r] = __int_as_float(__builtin_amdgcn_ds_bpermute(baddr[r], __float_as_int(z[r])));
        } else {
          const int nt = j - 2;
#pragma unroll
          for (int r = 0; r < 4; r++) {
            float bandc = __int_as_float(__builtin_amdgcn_ds_bpermute(baddr[r], __float_as_int(z[r])));
            Sc[0][nt][r] += bsel[r] ? bandc : bandp0[r];
            bandp0[r] = bandc;
          }
        }
      }
      // qi=1 uses this tile as window index j (only j<=4)
      if (j <= 4) {
        f32x4 z = (f32x4){0.f, 0.f, 0.f, 0.f};
        z = __builtin_amdgcn_mfma_f32_16x16x32_bf16(aqr[1][0], rf0, z, 0, 0, 0);
        z = __builtin_amdgcn_mfma_f32_16x16x32_bf16(aqr[1][1], rf1, z, 0, 0, 0);
        const int nt = j - 1;
#pragma unroll
        for (int r = 0; r < 4; r++) {
          float bandc = __int_as_float(__builtin_amdgcn_ds_bpermute(baddr[r], __float_as_int(z[r])));
          Sc[1][nt][r] += bsel[r] ? bandc : bandp1[r];
          bandp1[r] = bandc;
        }
      }
    }

    // ---- p = exp(logit); per-lane partial sums; P -> per-wave LDS slabs
#pragma unroll
    for (int nt = 0; nt < 4; nt++)
#pragma unroll
      for (int r = 0; r < 4; r++) {
        float pA = __expf(Sc[0][nt][r]);
        lrow[0][r] += pA;
        pwbA[(g * 4 + r) * 72 + nt * 16 + c] = f2b(pA);
        float pB = __expf(Sc[1][nt][r]);
        lrow[1][r] += pB;
        pwbB[(g * 4 + r) * 72 + nt * 16 + c] = f2b(pB);
      }
    // order P-write before P-read at the scheduler level while still letting
    // global loads / MFMA / VALU migrate across (0x7F = everything except DS)
    __builtin_amdgcn_sched_barrier(0x7F);
    bf16x8 apA0 = *(const bf16x8*)(pwbA + c * 72 + g * 8);
    bf16x8 apA1 = *(const bf16x8*)(pwbA + c * 72 + 32 + g * 8);
    bf16x8 apB0 = *(const bf16x8*)(pwbB + c * 72 + g * 8);
    bf16x8 apB1 = *(const bf16x8*)(pwbB + c * 72 + 32 + g * 8);
    __builtin_amdgcn_sched_barrier(0x7F);

    // ---- PV: each V fragment feeds BOTH q-tiles (1 load : 2 MFMA)
    __builtin_amdgcn_s_setprio(1);
#pragma unroll
    for (int nt3 = 0; nt3 < 12; nt3++) {
      const unsigned short* vrow = vtb + (size_t)(nt3 * 16 + c) * 1536 + j0;
      bf16x8 v0 = *(const bf16x8*)(vrow + g * 8);
      bf16x8 v1 = *(const bf16x8*)(vrow + 32 + g * 8);
      Ofr[0][nt3] = __builtin_amdgcn_mfma_f32_16x16x32_bf16(apA0, v0, Ofr[0][nt3], 0, 0, 0);
      Ofr[1][nt3] = __builtin_amdgcn_mfma_f32_16x16x32_bf16(apB0, v0, Ofr[1][nt3], 0, 0, 0);
      Ofr[0][nt3] = __builtin_amdgcn_mfma_f32_16x16x32_bf16(apA1, v1, Ofr[0][nt3], 0, 0, 0);
      Ofr[1][nt3] = __builtin_amdgcn_mfma_f32_16x16x32_bf16(apB1, v1, Ofr[1][nt3], 0, 0, 0);
    }
    __builtin_amdgcn_s_setprio(0);
  }

  // ---- one-time reduction of lrow over the 16 c-lanes of each row
#pragma unroll
  for (int qi = 0; qi < 2; qi++)
#pragma unroll
    for (int r = 0; r < 4; r++) {
      float s = lrow[qi][r];
      s += __shfl_xor(s, 1, 64);
      s += __shfl_xor(s, 2, 64);
      s += __shfl_xor(s, 4, 64);
      s += __shfl_xor(s, 8, 64);
      lrow[qi][r] = s;
    }
  // ---- cross-wave merge: scale = 1 / sum of 4 wave-sums (per qi)
  float* mll = smem + 9216;  // [qi*64 + w*16 + q], 128 floats
  if (c == 0)
#pragma unroll
    for (int qi = 0; qi < 2; qi++)
#pragma unroll
      for (int r = 0; r < 4; r++) mll[qi * 64 + w * 16 + g * 4 + r] = lrow[qi][r];
  __syncthreads();
  float scale[2][4];
#pragma unroll
  for (int qi = 0; qi < 2; qi++)
#pragma unroll
    for (int r = 0; r < 4; r++) {
      int q = qi * 64 + g * 4 + r;
      scale[qi][r] = 1.f / (mll[q] + mll[16 + q] + mll[32 + q] + mll[48 + q]);
    }
#pragma unroll
  for (int qi = 0; qi < 2; qi++)
#pragma unroll
    for (int t = 0; t < 12; t++)
#pragma unroll
      for (int r = 0; r < 4; r++) Ofr[qi][t][r] *= scale[qi][r];

  // chunked publish-sum per qi: 4 chunks of 3 v-tiles (48 cols); slots alias
  // the (dead) P bufs. All loops unrolled -> static Ofr indexing (no scratch).
  const int qo = tid >> 4, v3 = (tid & 15) * 3;
#pragma unroll
  for (int qi = 0; qi < 2; qi++) {
    unsigned short* orow =
        O + (size_t)(b * 1536 + i0b + qi * 16 + qo) * 1536 + h * 192;
#pragma unroll
    for (int c4 = 0; c4 < 4; c4++) {
      __syncthreads();
      float* slot = smem + w * 768;
#pragma unroll
      for (int tl = 0; tl < 3; tl++)
#pragma unroll
        for (int r = 0; r < 4; r++)
          slot[(g * 4 + r) * 48 + tl * 16 + c] = Ofr[qi][c4 * 3 + tl][r];
      __syncthreads();
#pragma unroll
      for (int k = 0; k < 3; k++) {
        int v = v3 + k;
        float s = smem[qo * 48 + v] + smem[768 + qo * 48 + v] +
                  smem[1536 + qo * 48 + v] + smem[2304 + qo * 48 + v];
        orow[c4 * 48 + v] = f2b(s);
      }
    }
  }
}

// ------------------------------------------------------------------ launcher
extern "C" void kernel_launch(void* const* d_in, const int* in_sizes, int n_in,
                              void* d_out, int out_size, void* d_ws, size_t ws_size,
                              hipStream_t stream) {
  const float* x    = (const float*)d_in[0];
  const float* Wq   = (const float*)d_in[1];
  const float* Wk   = (const float*)d_in[2];
  const float* Wv   = (const float*)d_in[3];
  const float* Wrk  = (const float*)d_in[4];
  const float* Wemb = (const float*)d_in[5];
  const float* rwb  = (const float*)d_in[6];
  const float* rrb  = (const float*)d_in[7];

  char* ws = (char*)d_ws;
  size_t off = 0;
  auto alloc = [&](size_t bytes) -> void* {
    void* p = ws + off;
    off += (bytes + 255) & ~(size_t)255;
    return p;
  };
  unsigned short* xb    = (unsigned short*)alloc((size_t)3072 * 1536 * 2);
  unsigned short* WqkvT = (unsigned short*)alloc((size_t)2560 * 1536 * 2);
  unsigned short* WembT = (unsigned short*)alloc((size_t)1536 * 1536 * 2);
  unsigned short* WrkT  = (unsigned short*)alloc((size_t)512 * 192 * 2);
  unsigned short* QKV   = (unsigned short*)alloc((size_t)3072 * 2560 * 2);
  unsigned short* Vt    = (unsigned short*)alloc((size_t)2 * 1536 * 1536 * 2);
  unsigned short* emb   = (unsigned short*)alloc((size_t)3072 * 192 * 2);
  unsigned short* rkb   = (unsigned short*)alloc((size_t)3072 * 512 * 2);
  unsigned short* Obuf  = (unsigned short*)alloc((size_t)3072 * 1536 * 2);

  // 1) fused prep: x->bf16, 5 weight transposes, positional emb (pmax const)
  k_prep<<<12000, 256, 0, stream>>>(x, Wq, Wk, Wv, Wemb, Wrk, xb, WqkvT, WembT, WrkT, emb);
  // 2) fused QKV projection
  k_gemm<<<dim3(20, 24), 256, 0, stream>>>(xb, WqkvT, QKV, nullptr, 3072, 2560, 1536);
  // 3) rel-key GEMM + V transposes
  k_mid<<<4704, 256, 0, stream>>>(emb, WrkT, rkb, QKV, Vt);
  // 4) flash attention (2 q-tiles/wave register reuse, wave-decoupled loop)
  k_attn<<<768, 256, 0, stream>>>(QKV, rkb, Vt, rwb, rrb, Obuf);
  // 5) output projection -> f32 d_out
  k_gemm<<<dim3(12, 24), 256, 0, stream>>>(Obuf, WembT, nullptr, (float*)d_out, 3072, 1536, 1536);
}

// Round 5
// 278.000 us; speedup vs baseline: 1.3778x; 1.1290x over previous
//
#include <hip/hip_runtime.h>
#include <stdint.h>

#define DEVI __device__ __forceinline__

typedef short bf16x8 __attribute__((ext_vector_type(8)));
typedef float f32x4 __attribute__((ext_vector_type(4)));

// analytically-derived max of the gamma positional basis (i=0, ap=36):
// exp(3*ln36 - 3 - ln6 - 4*ln12) = 0.01867013 (input-independent constant)
#define PMAX 0.01867013f

DEVI float b2f(unsigned short u) {
  union { unsigned u32; float f; } x;
  x.u32 = ((unsigned)u) << 16;
  return x.f;
}
DEVI unsigned short f2b(float f) {
  union { float f32; unsigned u32; } x;
  x.f32 = f;
  unsigned u = x.u32;
  return (unsigned short)((u + 0x7FFFu + ((u >> 16) & 1u)) >> 16);
}

// async global->LDS, 16B per lane. LDS dest must be wave-uniform base + lane*16.
DEVI void gload16(const unsigned short* g, unsigned short* l) {
  __builtin_amdgcn_global_load_lds(
      (const __attribute__((address_space(1))) void*)g,
      (__attribute__((address_space(3))) void*)l, 16, 0, 0);
}

DEVI float gamma_prob(float ap, int i) {
  float mean = 48.f * (float)(i + 1);
  float conc = (mean / 24.f) * (mean / 24.f);
  float rate = mean / 576.f;
  if (ap == 0.f) return 1e-8f;
  float logp = (conc - 1.f) * logf(ap) - rate * ap - (lgammaf(conc) - conc * logf(rate));
  return expf(logp) + 1e-8f;
}

// ---------------------------------------------------- device transpose (32x32)
DEVI void dev_transpose(const float* srcf, const unsigned short* srcb, int src_ld,
                        unsigned short* dst, int dst_ld, int rows, int cols,
                        int bx, int by, unsigned short (*t)[33]) {
  int tx = threadIdx.x & 31, ty = threadIdx.x >> 5;
  int r0 = by * 32, c0 = bx * 32;
#pragma unroll
  for (int i = 0; i < 4; i++) {
    int r = r0 + ty + i * 8, cc = c0 + tx;
    if (r < rows && cc < cols)
      t[ty + i * 8][tx] = srcf ? f2b(srcf[(size_t)r * src_ld + cc])
                               : srcb[(size_t)r * src_ld + cc];
  }
  __syncthreads();
#pragma unroll
  for (int i = 0; i < 4; i++) {
    int dr = c0 + ty + i * 8, dc = r0 + tx;
    if (dr < cols && dc < rows) dst[(size_t)dr * dst_ld + dc] = t[tx][ty + i * 8];
  }
}

// ------------------------------------------------------------------ k_prep
__global__ __launch_bounds__(256) void k_prep(
    const float* __restrict__ x, const float* __restrict__ Wq,
    const float* __restrict__ Wk, const float* __restrict__ Wv,
    const float* __restrict__ Wemb, const float* __restrict__ Wrk,
    unsigned short* __restrict__ xb, unsigned short* __restrict__ WqkvT,
    unsigned short* __restrict__ WembT, unsigned short* __restrict__ WrkT,
    unsigned short* __restrict__ emb) {
  __shared__ unsigned short t[32][33];
  int bid = blockIdx.x;
  if (bid < 4608) {
    int i = (bid * 256 + threadIdx.x) * 4;
    float4 v = *(const float4*)(x + i);
    ushort4 o;
    o.x = f2b(v.x); o.y = f2b(v.y); o.z = f2b(v.z); o.w = f2b(v.w);
    *(ushort4*)(xb + i) = o;
  } else if (bid < 5376) {
    int s = bid - 4608;
    dev_transpose(Wq, nullptr, 512, WqkvT, 1536, 1536, 512, s % 16, s / 16, t);
  } else if (bid < 6144) {
    int s = bid - 5376;
    dev_transpose(Wk, nullptr, 512, WqkvT + (size_t)512 * 1536, 1536, 1536, 512, s % 16, s / 16, t);
  } else if (bid < 8448) {
    int s = bid - 6144;
    dev_transpose(Wv, nullptr, 1536, WqkvT + (size_t)1024 * 1536, 1536, 1536, 1536, s % 48, s / 48, t);
  } else if (bid < 10752) {
    int s = bid - 8448;
    dev_transpose(Wemb, nullptr, 1536, WembT, 1536, 1536, 1536, s % 48, s / 48, t);
  } else if (bid < 10848) {
    int s = bid - 10752;
    dev_transpose(Wrk, nullptr, 512, WrkT, 192, 192, 512, s % 16, s / 16, t);
  } else {
    int idx = (bid - 10848) * 256 + threadIdx.x;
    if (idx < 3071 * 96) {
      int m = idx / 96, cc = idx % 96;
      float ap = fabsf((float)(m - 1535));
      float val;
      if (cc < 32) {
        float max_range = logf(1536.f) * 1.4426950408889634f;
        float l = 3.f + (float)cc * (max_range - 3.f) / 31.f;
        val = exp2f(-ap * exp2f(-l));
      } else if (cc < 64) {
        float width = exp2f((float)(cc - 31)) - 1.f;
        val = (width > ap) ? 1.f : 0.f;
      } else {
        val = gamma_prob(ap, cc - 64) / PMAX;
      }
      float sgn = (m > 1535) ? 1.f : ((m < 1535) ? -1.f : 0.f);
      emb[(size_t)m * 192 + cc] = f2b(val);
      emb[(size_t)m * 192 + 96 + cc] = f2b(sgn * val);
    }
  }
}

// ---------------------------------------------------------------- MFMA GEMM
DEVI void dev_gemm(const unsigned short* __restrict__ A, const unsigned short* __restrict__ Bt,
                   unsigned short* Cb, float* Cf, int M, int N, int K,
                   int bx, int by, unsigned short* As, unsigned short* Bs) {
  int tid = threadIdx.x;
  int w = tid >> 6, L = tid & 63, g = L >> 4, c = L & 15;
  int m0 = by << 7, n0 = bx << 7;
  int wm = (w >> 1) << 6, wn = (w & 1) << 6;
  f32x4 acc[4][4];
#pragma unroll
  for (int i = 0; i < 4; i++)
#pragma unroll
    for (int j = 0; j < 4; j++) acc[i][j] = (f32x4){0.f, 0.f, 0.f, 0.f};
  int nkt = K >> 5;
  for (int kt = 0; kt < nkt; kt++) {
    int k0 = kt << 5;
#pragma unroll
    for (int i2 = 0; i2 < 2; i2++) {
      int cidx = tid + (i2 << 8);
      int row = cidx >> 2, kc = (cidx & 3) << 3;
      int ra = m0 + row;
      if (ra >= M) ra = M - 1;
      gload16(A + (size_t)ra * K + k0 + kc, As + cidx * 8);
      gload16(Bt + (size_t)(n0 + row) * K + k0 + kc, Bs + cidx * 8);
    }
    __syncthreads();
    bf16x8 af[4], bfr[4];
#pragma unroll
    for (int t = 0; t < 4; t++) af[t] = *(const bf16x8*)(As + (wm + t * 16 + c) * 32 + g * 8);
#pragma unroll
    for (int t = 0; t < 4; t++) bfr[t] = *(const bf16x8*)(Bs + (wn + t * 16 + c) * 32 + g * 8);
#pragma unroll
    for (int mt = 0; mt < 4; mt++)
#pragma unroll
      for (int nt = 0; nt < 4; nt++)
        acc[mt][nt] = __builtin_amdgcn_mfma_f32_16x16x32_bf16(af[mt], bfr[nt], acc[mt][nt], 0, 0, 0);
    __syncthreads();
  }
#pragma unroll
  for (int mt = 0; mt < 4; mt++)
#pragma unroll
    for (int nt = 0; nt < 4; nt++)
#pragma unroll
      for (int r = 0; r < 4; r++) {
        int rr = m0 + wm + mt * 16 + g * 4 + r;
        if (rr < M) {
          size_t o = (size_t)rr * N + n0 + wn + nt * 16 + c;
          if (Cf) Cf[o] = acc[mt][nt][r];
          else Cb[o] = f2b(acc[mt][nt][r]);
        }
      }
}

__global__ __launch_bounds__(256) void k_gemm(
    const unsigned short* __restrict__ A, const unsigned short* __restrict__ Bt,
    unsigned short* Cb, float* Cf, int M, int N, int K) {
  __shared__ unsigned short sm[8192];
  dev_gemm(A, Bt, Cb, Cf, M, N, K, blockIdx.x, blockIdx.y, sm, sm + 4096);
}

// ------------------------------------------------------------------ k_mid
__global__ __launch_bounds__(256) void k_mid(
    const unsigned short* __restrict__ emb, const unsigned short* __restrict__ WrkT,
    unsigned short* __restrict__ rkb, const unsigned short* __restrict__ QKV,
    unsigned short* __restrict__ Vt) {
  __shared__ unsigned short sm[8192];
  int bid = blockIdx.x;
  if (bid < 96) {
    dev_gemm(emb, WrkT, rkb, nullptr, 3071, 512, 192, bid & 3, bid >> 2, sm, sm + 4096);
  } else {
    int tt = bid - 96;
    int which = tt / 2304;
    tt %= 2304;
    dev_transpose(nullptr, QKV + 1024 + (size_t)which * 1536 * 2560, 2560,
                  Vt + (size_t)which * 1536 * 1536, 1536, 1536, 1536,
                  tt % 48, tt / 48, (unsigned short (*)[33])sm);
  }
}

// ------------------------------------------------------------ flash attention
// r5: FLASH RESTRUCTURE. r4 confirmed per-wave L2-fill traffic is the control
// variable (1.85x traffic cut -> 1.35x). Register wall forbids >2 q-tiles/wave,
// so amortize via LDS: P slabs for 8 q-tiles let ONE staged V tile serve 128
// q-rows (16x better V bytes/q than r4). QBLK=128, key-split=2 (grid 384 =
// 2kh x 2b x 8h x 12qb; bid&7=h keeps XCD swizzle; all blocks resident).
// 4 waves: score phase = r4's verified 2-q-tile union-rel code (wave w owns
// q-tiles 2w,2w+1); PV phase = vdim-split (wave w owns vdims [48w,48w+48) x
// all 8 P slabs). K(dbuf)+V(single) staged via coalesced global_load_lds with
// both-sides XOR swizzle (linear LDS dest + pre-swizzled global src + swizzled
// ds_read; involution byte^=((row&7)<<4)). P slabs stride-64u16 + same swizzle.
// 2 syncthreads/jt: MID (P visible + V/K DMA drained -- V needs the drain
// anyway so the vmcnt(0) is free), END (PV ds_reads done before next V stage).
// Key-split => unnormalized f32 O-partials + l-partials; k_fin merges.
// Traffic: 80KB/block-jt x 12 x 384 = 0.37GB (0.46x of r4), full-line requests.
__global__ __launch_bounds__(256, 2) void k_attn(
    const unsigned short* __restrict__ QKV, const unsigned short* __restrict__ rk,
    const unsigned short* __restrict__ Vt, const float* __restrict__ rwb,
    const float* __restrict__ rrb, float* __restrict__ Opart,
    float* __restrict__ lpart) {
  // u16 layout: K dbuf [0,8192) (2x4096); V [8192,20480); P slabs [20480,28672)
  __shared__ unsigned short lds[28672];
  const int tid = threadIdx.x;
  const int w = tid >> 6, L = tid & 63, g = L >> 4, c = L & 15;
  const int bid = blockIdx.x;
  const int h = bid & 7, b = (bid >> 3) & 1, kh = (bid >> 4) & 1;
  const int i0b = (bid >> 5) << 7;   // 128-row q-block base
  const int qp = i0b + w * 32;       // this wave's 32-row q-pair base
  const int bh = b * 8 + h;
  const int c7s = (c & 7) << 3;      // u16-index swizzle term for reads

  // staging lane decode (shared by K and V stages)
  const int lrow8 = L >> 3;                                // 0..7
  const int lbo = (((L & 7) * 16) ^ ((lrow8 & 7) << 4));   // swizzled byte in 128B row

  // Q fragments for both q-subtiles: [qi][ks]; content uses rwb, rel uses rrb
  bf16x8 aqw[2][2], aqr[2][2];
#pragma unroll
  for (int qi = 0; qi < 2; qi++) {
    const unsigned short* qrow =
        QKV + (size_t)(b * 1536 + qp + qi * 16 + c) * 2560 + h * 64;
#pragma unroll
    for (int ks = 0; ks < 2; ks++) {
      union { bf16x8 v; unsigned short s[8]; } uw, ur;
#pragma unroll
      for (int j = 0; j < 8; j++) {
        int d = ks * 32 + g * 8 + j;
        float qv = b2f(qrow[d]) * 0.125f;
        uw.s[j] = f2b(qv + rwb[h * 64 + d]);
        ur.s[j] = f2b(qv + rrb[h * 64 + d]);
      }
      aqw[qi][ks] = uw.v;
      aqr[qi][ks] = ur.v;
    }
  }

  // bpermute addresses / selects for the folded relative shift
  int baddr[4], bsel[4];
#pragma unroll
  for (int r = 0; r < 4; r++) {
    int u = c - (g * 4 + r) + 15;  // in [0,30]
    baddr[r] = (((g << 4) | (u & 15)) << 2);
    bsel[r] = (u >> 4) & 1;
  }

  f32x4 Ofr[8][3];  // [q-slab][v-tile of this wave's 48 vdims]
#pragma unroll
  for (int s = 0; s < 8; s++)
#pragma unroll
    for (int t = 0; t < 3; t++) Ofr[s][t] = (f32x4){0.f, 0.f, 0.f, 0.f};
  float lrow[2][4] = {{0.f, 0.f, 0.f, 0.f}, {0.f, 0.f, 0.f, 0.f}};

  const unsigned short* rkh = rk + h * 64;
  const size_t kgbase = (size_t)(b * 1536 + kh * 768) * 2560 + 512 + h * 64;
  const size_t vgbase = (size_t)(bh * 192) * 1536 + kh * 768;

  // ---- staging helpers (wave w covers its share; dest wave-uniform) ----
  auto stageK = [&](int kt, int nb) {
#pragma unroll
    for (int i = 0; i < 2; i++) {
      int key = w * 16 + i * 8 + lrow8;
      const unsigned short* src =
          QKV + kgbase + (size_t)(kt * 64 + key) * 2560 + (lbo >> 1);
      gload16(src, lds + nb * 4096 + w * 1024 + i * 512);
    }
  };
  auto stageV = [&](int kt) {
#pragma unroll
    for (int i = 0; i < 6; i++) {
      int vd = w * 48 + i * 8 + lrow8;
      const unsigned short* src =
          Vt + vgbase + (size_t)vd * 1536 + kt * 64 + (lbo >> 1);
      gload16(src, lds + 8192 + w * 3072 + i * 512);
    }
  };

  stageK(0, 0);
  __syncthreads();

  for (int jt = 0; jt < 12; jt++) {
    const int cur = jt & 1;
    // issue V(jt) + K(jt+1) DMA; both drain at the MID barrier
    stageV(jt);
    if (jt < 11) stageK(jt + 1, cur ^ 1);

    const int j0g = kh * 768 + jt * 64;
    const int moff1 = j0g - (qp + 16) + 1520;  // rel-window base for qi=1
    const unsigned short* kb = lds + cur * 4096;

    // ---- content scores: each K fragment (from LDS) feeds BOTH q-tiles
    f32x4 Sc[2][4];
#pragma unroll
    for (int nt = 0; nt < 4; nt++) {
      const int kro = (nt * 16 + c) * 64;
      bf16x8 kf0 = *(const bf16x8*)(kb + kro + ((g * 8) ^ c7s));
      bf16x8 kf1 = *(const bf16x8*)(kb + kro + ((32 + g * 8) ^ c7s));
      f32x4 z0 = (f32x4){0.f, 0.f, 0.f, 0.f};
      z0 = __builtin_amdgcn_mfma_f32_16x16x32_bf16(aqw[0][0], kf0, z0, 0, 0, 0);
      z0 = __builtin_amdgcn_mfma_f32_16x16x32_bf16(aqw[0][1], kf1, z0, 0, 0, 0);
      Sc[0][nt] = z0;
      f32x4 z1 = (f32x4){0.f, 0.f, 0.f, 0.f};
      z1 = __builtin_amdgcn_mfma_f32_16x16x32_bf16(aqw[1][0], kf0, z1, 0, 0, 0);
      z1 = __builtin_amdgcn_mfma_f32_16x16x32_bf16(aqw[1][1], kf1, z1, 0, 0, 0);
      Sc[1][nt] = z1;
    }

    // ---- rel band: union pass over 6 rk tiles serves both windows (r4 code)
    float bandp0[4], bandp1[4];
    {  // j = 0: qi=1 initial only
      int mg = moff1 + c;
      const unsigned short* rrow = rkh + (size_t)mg * 512;
      f32x4 z = (f32x4){0.f, 0.f, 0.f, 0.f};
      z = __builtin_amdgcn_mfma_f32_16x16x32_bf16(aqr[1][0], *(const bf16x8*)(rrow + g * 8), z, 0, 0, 0);
      z = __builtin_amdgcn_mfma_f32_16x16x32_bf16(aqr[1][1], *(const bf16x8*)(rrow + 32 + g * 8), z, 0, 0, 0);
#pragma unroll
      for (int r = 0; r < 4; r++)
        bandp1[r] = __int_as_float(__builtin_amdgcn_ds_bpermute(baddr[r], __float_as_int(z[r])));
    }
#pragma unroll
    for (int j = 1; j <= 5; j++) {
      int mg = moff1 + 16 * j + c;
      if (mg > 3070) mg = 3070;  // clamped lane feeds only unused band slots
      const unsigned short* rrow = rkh + (size_t)mg * 512;
      bf16x8 rf0 = *(const bf16x8*)(rrow + g * 8);
      bf16x8 rf1 = *(const bf16x8*)(rrow + 32 + g * 8);
      {  // qi=0 uses this tile as window index j-1
        f32x4 z = (f32x4){0.f, 0.f, 0.f, 0.f};
        z = __builtin_amdgcn_mfma_f32_16x16x32_bf16(aqr[0][0], rf0, z, 0, 0, 0);
        z = __builtin_amdgcn_mfma_f32_16x16x32_bf16(aqr[0][1], rf1, z, 0, 0, 0);
        if (j == 1) {
#pragma unroll
          for (int r = 0; r < 4; r++)
            bandp0[r] = __int_as_float(__builtin_amdgcn_ds_bpermute(baddr[r], __float_as_int(z[r])));
        } else {
          const int nt = j - 2;
#pragma unroll
          for (int r = 0; r < 4; r++) {
            float bandc = __int_as_float(__builtin_amdgcn_ds_bpermute(baddr[r], __float_as_int(z[r])));
            Sc[0][nt][r] += bsel[r] ? bandc : bandp0[r];
            bandp0[r] = bandc;
          }
        }
      }
      if (j <= 4) {  // qi=1 uses this tile as window index j
        f32x4 z = (f32x4){0.f, 0.f, 0.f, 0.f};
        z = __builtin_amdgcn_mfma_f32_16x16x32_bf16(aqr[1][0], rf0, z, 0, 0, 0);
        z = __builtin_amdgcn_mfma_f32_16x16x32_bf16(aqr[1][1], rf1, z, 0, 0, 0);
        const int nt = j - 1;
#pragma unroll
        for (int r = 0; r < 4; r++) {
          float bandc = __int_as_float(__builtin_amdgcn_ds_bpermute(baddr[r], __float_as_int(z[r])));
          Sc[1][nt][r] += bsel[r] ? bandc : bandp1[r];
          bandp1[r] = bandc;
        }
      }
    }

    // ---- p = exp(logit); per-lane partial sums; P -> swizzled slabs 2w,2w+1
#pragma unroll
    for (int qi = 0; qi < 2; qi++) {
      unsigned short* slab = lds + 20480 + (2 * w + qi) * 1024;
#pragma unroll
      for (int nt = 0; nt < 4; nt++)
#pragma unroll
        for (int r = 0; r < 4; r++) {
          float p = __expf(Sc[qi][nt][r]);
          lrow[qi][r] += p;
          int q = g * 4 + r;
          slab[q * 64 + ((nt * 16 + c) ^ ((q & 7) << 3))] = f2b(p);
        }
    }

    __syncthreads();  // P visible to all waves; V(jt)/K(jt+1) DMA drained

    // ---- PV: staged V tile serves ALL 8 q-slabs (this wave's 48 vdims)
    bf16x8 vf0[3], vf1[3];
#pragma unroll
    for (int vt = 0; vt < 3; vt++) {
      const int vro = 8192 + (w * 48 + vt * 16 + c) * 64;
      vf0[vt] = *(const bf16x8*)(lds + vro + ((g * 8) ^ c7s));
      vf1[vt] = *(const bf16x8*)(lds + vro + ((32 + g * 8) ^ c7s));
    }
    __builtin_amdgcn_s_setprio(1);
#pragma unroll
    for (int s = 0; s < 8; s++) {
      const unsigned short* slab = lds + 20480 + s * 1024;
      bf16x8 ap0 = *(const bf16x8*)(slab + c * 64 + ((g * 8) ^ c7s));
      bf16x8 ap1 = *(const bf16x8*)(slab + c * 64 + ((32 + g * 8) ^ c7s));
#pragma unroll
      for (int vt = 0; vt < 3; vt++) {
        Ofr[s][vt] = __builtin_amdgcn_mfma_f32_16x16x32_bf16(ap0, vf0[vt], Ofr[s][vt], 0, 0, 0);
        Ofr[s][vt] = __builtin_amdgcn_mfma_f32_16x16x32_bf16(ap1, vf1[vt], Ofr[s][vt], 0, 0, 0);
      }
    }
    __builtin_amdgcn_s_setprio(0);

    __syncthreads();  // PV ds_reads done before next jt's V stage overwrites
  }

  // ---- l partials: reduce lrow over the 16 c-lanes, write global (no merge)
#pragma unroll
  for (int qi = 0; qi < 2; qi++)
#pragma unroll
    for (int r = 0; r < 4; r++) {
      float s = lrow[qi][r];
      s += __shfl_xor(s, 1, 64);
      s += __shfl_xor(s, 2, 64);
      s += __shfl_xor(s, 4, 64);
      s += __shfl_xor(s, 8, 64);
      lrow[qi][r] = s;
    }
  if (c == 0) {
#pragma unroll
    for (int qi = 0; qi < 2; qi++)
#pragma unroll
      for (int r = 0; r < 4; r++)
        lpart[(size_t)((kh * 2 + b) * 8 + h) * 1536 + qp + qi * 16 + g * 4 + r] =
            lrow[qi][r];
  }
  // ---- O partials (unnormalized f32); waves own disjoint vdim ranges
#pragma unroll
  for (int s = 0; s < 8; s++)
#pragma unroll
    for (int vt = 0; vt < 3; vt++)
#pragma unroll
      for (int r = 0; r < 4; r++)
        Opart[(size_t)(kh * 3072 + b * 1536 + i0b + s * 16 + g * 4 + r) * 1536 +
              h * 192 + w * 48 + vt * 16 + c] = Ofr[s][vt][r];
}

// ------------------------------------------------------- key-split finalize
// out_bf16[row][col] = (O0+O1)[row][col] / (l0+l1)[kh sums]; 8 cols/thread.
__global__ __launch_bounds__(256) void k_fin(
    const float* __restrict__ Op, const float* __restrict__ lp,
    unsigned short* __restrict__ O) {
  int idx = (blockIdx.x * 256 + threadIdx.x) * 8;
  int row = idx / 1536, c0 = idx % 1536;
  int b = row >> 11 ? 1 : (row >= 1536);  // row in [0,3072)
  b = row >= 1536;
  int q = row - b * 1536, hh = c0 / 192;
  float l = lp[(size_t)(b * 8 + hh) * 1536 + q] +
            lp[(size_t)((2 + b) * 8 + hh) * 1536 + q];
  float sc = 1.f / l;
  const float4* p0 = (const float4*)(Op + (size_t)row * 1536 + c0);
  const float4* p1 = (const float4*)(Op + (size_t)(3072 + row) * 1536 + c0);
#pragma unroll
  for (int half = 0; half < 2; half++) {
    float4 a = p0[half], bb = p1[half];
    ushort4 o;
    o.x = f2b((a.x + bb.x) * sc);
    o.y = f2b((a.y + bb.y) * sc);
    o.z = f2b((a.z + bb.z) * sc);
    o.w = f2b((a.w + bb.w) * sc);
    *(ushort4*)(O + (size_t)row * 1536 + c0 + half * 4) = o;
  }
}

// ------------------------------------------------------------------ launcher
extern "C" void kernel_launch(void* const* d_in, const int* in_sizes, int n_in,
                              void* d_out, int out_size, void* d_ws, size_t ws_size,
                              hipStream_t stream) {
  const float* x    = (const float*)d_in[0];
  const float* Wq   = (const float*)d_in[1];
  const float* Wk   = (const float*)d_in[2];
  const float* Wv   = (const float*)d_in[3];
  const float* Wrk  = (const float*)d_in[4];
  const float* Wemb = (const float*)d_in[5];
  const float* rwb  = (const float*)d_in[6];
  const float* rrb  = (const float*)d_in[7];

  char* ws = (char*)d_ws;
  size_t off = 0;
  auto alloc = [&](size_t bytes) -> void* {
    void* p = ws + off;
    off += (bytes + 255) & ~(size_t)255;
    return p;
  };
  unsigned short* xb    = (unsigned short*)alloc((size_t)3072 * 1536 * 2);
  unsigned short* WqkvT = (unsigned short*)alloc((size_t)2560 * 1536 * 2);
  unsigned short* WembT = (unsigned short*)alloc((size_t)1536 * 1536 * 2);
  unsigned short* WrkT  = (unsigned short*)alloc((size_t)512 * 192 * 2);
  unsigned short* QKV   = (unsigned short*)alloc((size_t)3072 * 2560 * 2);
  unsigned short* Vt    = (unsigned short*)alloc((size_t)2 * 1536 * 1536 * 2);
  unsigned short* emb   = (unsigned short*)alloc((size_t)3072 * 192 * 2);
  unsigned short* rkb   = (unsigned short*)alloc((size_t)3072 * 512 * 2);
  unsigned short* Obuf  = (unsigned short*)alloc((size_t)3072 * 1536 * 2);
  float*          Opart = (float*)alloc((size_t)2 * 3072 * 1536 * 4);
  float*          lpart = (float*)alloc((size_t)2 * 2 * 8 * 1536 * 4);

  // 1) fused prep: x->bf16, 5 weight transposes, positional emb (pmax const)
  k_prep<<<12000, 256, 0, stream>>>(x, Wq, Wk, Wv, Wemb, Wrk, xb, WqkvT, WembT, WrkT, emb);
  // 2) fused QKV projection
  k_gemm<<<dim3(20, 24), 256, 0, stream>>>(xb, WqkvT, QKV, nullptr, 3072, 2560, 1536);
  // 3) rel-key GEMM + V transposes
  k_mid<<<4704, 256, 0, stream>>>(emb, WrkT, rkb, QKV, Vt);
  // 4) flash attention (QBLK=128, key-split=2, staged K/V, P-in-LDS PV)
  k_attn<<<384, 256, 0, stream>>>(QKV, rkb, Vt, rwb, rrb, Opart, lpart);
  // 5) merge key-split partials -> Obuf bf16
  k_fin<<<2304, 256, 0, stream>>>(Opart, lpart, Obuf);
  // 6) output projection -> f32 d_out
  k_gemm<<<dim3(12, 24), 256, 0, stream>>>(Obuf, WembT, nullptr, (float*)d_out, 3072, 1536, 1536);
}